// Round 3
// baseline (265.038 us; speedup 1.0000x reference)
//
#include <hip/hip_runtime.h>
#include <math.h>

#define HDIM   768
#define NSAMP  512
#define NLOG   513            // 1 target + 512 noise
#define VOCAB  50257

// ---------------------------------------------------------------------------
// Sorted-gather pipeline:
//  A) zero histogram counts
//  B) histogram of all 525312 vocab indices (atomics, ~10 per bin)
//  C) single-block exclusive prefix sum over 50257 bins -> cursor
//  D) scatter: stable-enough counting sort of (vocab, payload) pairs
//  E) gather-dot: wave walks 64 sorted occurrences; W row loaded once per run
//     (avg run ~10.4), h row gathered per occurrence (3 MB, L2-resident)
//  F) per-token log-softmax + smoothed loss
//  G) deterministic mean
// ---------------------------------------------------------------------------

__global__ __launch_bounds__(256) void zero_kernel(unsigned int* __restrict__ p, int n)
{
    int i = blockIdx.x * 256 + threadIdx.x;
    int stride = gridDim.x * 256;
    for (; i < n; i += stride) p[i] = 0u;
}

__global__ __launch_bounds__(256) void hist_kernel(
    const int* __restrict__ target, const int* __restrict__ noise,
    unsigned int* __restrict__ counts, int N)
{
    int i = blockIdx.x * 256 + threadIdx.x;
    int stride = gridDim.x * 256;
    const int nn = N * NSAMP;
    for (int k = i; k < nn; k += stride) atomicAdd(&counts[noise[k]], 1u);
    for (int k = i; k < N;  k += stride) atomicAdd(&counts[target[k]], 1u);
}

// single block, 1024 threads, chunked Hillis-Steele scan
__global__ __launch_bounds__(1024) void scan_kernel(
    const unsigned int* __restrict__ counts, unsigned int* __restrict__ cursor)
{
    const int tid = threadIdx.x;
    const int CH  = (VOCAB + 1023) / 1024;       // 50
    const int lo  = tid * CH;
    const int hi  = (lo + CH < VOCAB) ? lo + CH : VOCAB;

    __shared__ unsigned int lds[1024];
    unsigned int s = 0;
    for (int i = lo; i < hi; ++i) s += counts[i];
    lds[tid] = s;
    __syncthreads();
    for (int off = 1; off < 1024; off <<= 1) {
        unsigned int t = (tid >= off) ? lds[tid - off] : 0u;
        __syncthreads();
        lds[tid] += t;
        __syncthreads();
    }
    unsigned int run = (tid > 0) ? lds[tid - 1] : 0u;   // exclusive prefix
    for (int i = lo; i < hi; ++i) { cursor[i] = run; run += counts[i]; }
}

__global__ __launch_bounds__(256) void scatter_kernel(
    const int* __restrict__ target, const int* __restrict__ noise,
    unsigned int* __restrict__ cursor,
    unsigned int* __restrict__ sorted_v, unsigned int* __restrict__ sorted_pay, int N)
{
    int i = blockIdx.x * 256 + threadIdx.x;
    int stride = gridDim.x * 256;
    const int nn = N * NSAMP;
    for (int k = i; k < nn; k += stride) {
        const int v    = noise[k];
        const int tok  = k >> 9;            // /512
        const int slot = (k & 511) + 1;     // noise -> slots 1..512
        const unsigned int pos = atomicAdd(&cursor[v], 1u);
        sorted_v[pos]   = (unsigned int)v;
        sorted_pay[pos] = ((unsigned int)tok << 10) | (unsigned int)slot;
    }
    for (int k = i; k < N; k += stride) {
        const int v = target[k];
        const unsigned int pos = atomicAdd(&cursor[v], 1u);
        sorted_v[pos]   = (unsigned int)v;
        sorted_pay[pos] = ((unsigned int)k << 10);   // slot 0
    }
}

#define GTPB 512
__global__ __launch_bounds__(GTPB) void gather_dot_kernel(
    const float* __restrict__ h, const float* __restrict__ W,
    const unsigned int* __restrict__ sorted_v,
    const unsigned int* __restrict__ sorted_pay,
    float* __restrict__ logits, int nocc)
{
    const int lane    = threadIdx.x & 63;
    const int wave_id = (blockIdx.x * (GTPB / 64)) + (threadIdx.x >> 6);
    const int base    = wave_id * 64;
    if (base >= nocc) return;
    const int cnt = (nocc - base < 64) ? (nocc - base) : 64;

    const int idx = (base + lane < nocc) ? base + lane : nocc - 1;
    const int v_l = (int)sorted_v[idx];
    const int p_l = (int)sorted_pay[idx];

    int vprev = -1;
    float4 w0, w1, w2;
    for (int j = 0; j < cnt; ++j) {
        const int vv = __shfl(v_l, j, 64);
        const int pp = __shfl(p_l, j, 64);
        if (vv != vprev) {
            vprev = vv;
            const float4* wr = reinterpret_cast<const float4*>(W + (size_t)vv * HDIM);
            w0 = wr[lane]; w1 = wr[lane + 64]; w2 = wr[lane + 128];
        }
        const int tok  = pp >> 10;
        const int slot = pp & 1023;
        const float4* hr = reinterpret_cast<const float4*>(h + (size_t)tok * HDIM);
        const float4 a0 = hr[lane];
        const float4 a1 = hr[lane + 64];
        const float4 a2 = hr[lane + 128];
        float s;
        s  = w0.x * a0.x + w0.y * a0.y + w0.z * a0.z + w0.w * a0.w;
        s += w1.x * a1.x + w1.y * a1.y + w1.z * a1.z + w1.w * a1.w;
        s += w2.x * a2.x + w2.y * a2.y + w2.z * a2.z + w2.w * a2.w;
        #pragma unroll
        for (int off = 32; off; off >>= 1) s += __shfl_xor(s, off, 64);
        if (lane == 0) logits[tok * NLOG + slot] = s;
    }
}

__global__ __launch_bounds__(256) void softmax_loss_kernel(
    const float* __restrict__ logits, float* __restrict__ loss_per_token)
{
    const int n    = blockIdx.x;
    const int tid  = threadIdx.x;
    const int lane = tid & 63;
    const int wave = tid >> 6;
    const float* row = logits + (size_t)n * NLOG;

    __shared__ float red[4];
    __shared__ float red2[4][2];

    float lmax = -INFINITY;
    for (int r = tid; r < NLOG; r += 256) lmax = fmaxf(lmax, row[r]);
    #pragma unroll
    for (int off = 32; off; off >>= 1) lmax = fmaxf(lmax, __shfl_xor(lmax, off, 64));
    if (lane == 0) red[wave] = lmax;
    __syncthreads();
    lmax = fmaxf(fmaxf(red[0], red[1]), fmaxf(red[2], red[3]));

    float esum = 0.f, lsum = 0.f;
    for (int r = tid; r < NLOG; r += 256) {
        const float l = row[r];
        esum += __expf(l - lmax);
        if (r > 0) lsum += l;
    }
    #pragma unroll
    for (int off = 32; off; off >>= 1) {
        esum += __shfl_xor(esum, off, 64);
        lsum += __shfl_xor(lsum, off, 64);
    }
    if (lane == 0) { red2[wave][0] = esum; red2[wave][1] = lsum; }
    __syncthreads();

    if (tid == 0) {
        esum = red2[0][0] + red2[1][0] + red2[2][0] + red2[3][0];
        lsum = red2[0][1] + red2[1][1] + red2[2][1] + red2[3][1];
        const float lse  = lmax + logf(esum);
        const float l0   = row[0];
        const float loss = -0.9f * (l0 - lse)
                         - (0.1f / 512.f) * (lsum - 512.f * lse);
        loss_per_token[n] = loss;
    }
}

__global__ __launch_bounds__(256) void reduce_mean_kernel(
    const float* __restrict__ x, float* __restrict__ out, int n)
{
    const int tid = threadIdx.x;
    float s = 0.f;
    for (int i = tid; i < n; i += 256) s += x[i];
    #pragma unroll
    for (int off = 32; off; off >>= 1) s += __shfl_xor(s, off, 64);
    __shared__ float red[4];
    if ((tid & 63) == 0) red[tid >> 6] = s;
    __syncthreads();
    if (tid == 0) out[0] = (red[0] + red[1] + red[2] + red[3]) / (float)n;
}

// ------------------------- legacy fallback (R1) ----------------------------
__global__ __launch_bounds__(512) void nce_token_kernel(
    const float* __restrict__ h, const float* __restrict__ W,
    const int* __restrict__ target, const int* __restrict__ noise,
    float* __restrict__ loss_per_token)
{
    const int n    = blockIdx.x;
    const int tid  = threadIdx.x;
    const int lane = tid & 63;
    const int wave = tid >> 6;

    __shared__ float  logits[NLOG];
    __shared__ float4 hsm[HDIM / 4];
    __shared__ float  red[8];
    __shared__ float  red2[8][2];

    const float4* hrow = reinterpret_cast<const float4*>(h + (size_t)n * HDIM);
    if (tid < HDIM / 4) hsm[tid] = hrow[tid];
    __syncthreads();

    const float4 h0 = hsm[lane];
    const float4 h1 = hsm[lane + 64];
    const float4 h2 = hsm[lane + 128];
    const int* nrow = noise + (size_t)n * NSAMP;

    for (int r = wave; r < NLOG; r += 8) {
        const int row = (r == 0) ? target[n] : nrow[r - 1];
        const float4* wr = reinterpret_cast<const float4*>(W + (size_t)row * HDIM);
        const float4 w0 = wr[lane];
        const float4 w1 = wr[lane + 64];
        const float4 w2 = wr[lane + 128];
        float s;
        s  = h0.x * w0.x + h0.y * w0.y + h0.z * w0.z + h0.w * w0.w;
        s += h1.x * w1.x + h1.y * w1.y + h1.z * w1.z + h1.w * w1.w;
        s += h2.x * w2.x + h2.y * w2.y + h2.z * w2.z + h2.w * w2.w;
        #pragma unroll
        for (int off = 32; off; off >>= 1) s += __shfl_xor(s, off, 64);
        if (lane == 0) logits[r] = s;
    }
    __syncthreads();

    float lmax = -INFINITY;
    for (int r = tid; r < NLOG; r += 512) lmax = fmaxf(lmax, logits[r]);
    #pragma unroll
    for (int off = 32; off; off >>= 1) lmax = fmaxf(lmax, __shfl_xor(lmax, off, 64));
    if (lane == 0) red[wave] = lmax;
    __syncthreads();
    if (wave == 0) {
        float m = (lane < 8) ? red[lane] : -INFINITY;
        #pragma unroll
        for (int off = 4; off; off >>= 1) m = fmaxf(m, __shfl_xor(m, off, 64));
        if (lane == 0) red[0] = m;
    }
    __syncthreads();
    lmax = red[0];

    float esum = 0.f, lsum = 0.f;
    for (int r = tid; r < NLOG; r += 512) {
        const float l = logits[r];
        esum += __expf(l - lmax);
        if (r > 0) lsum += l;
    }
    #pragma unroll
    for (int off = 32; off; off >>= 1) {
        esum += __shfl_xor(esum, off, 64);
        lsum += __shfl_xor(lsum, off, 64);
    }
    if (lane == 0) { red2[wave][0] = esum; red2[wave][1] = lsum; }
    __syncthreads();

    if (tid == 0) {
        esum = 0.f; lsum = 0.f;
        #pragma unroll
        for (int w = 0; w < 8; ++w) { esum += red2[w][0]; lsum += red2[w][1]; }
        const float lse  = lmax + logf(esum);
        const float loss = -0.9f * (logits[0] - lse)
                         - (0.1f / 512.f) * (lsum - 512.f * lse);
        loss_per_token[n] = loss;
    }
}
// ---------------------------------------------------------------------------

extern "C" void kernel_launch(void* const* d_in, const int* in_sizes, int n_in,
                              void* d_out, int out_size, void* d_ws, size_t ws_size,
                              hipStream_t stream)
{
    const float* h      = (const float*)d_in[0];   // [N, 768] fp32
    const float* W      = (const float*)d_in[1];   // [50257, 768] fp32
    const int*   target = (const int*)d_in[2];     // [N] int32
    const int*   noise  = (const int*)d_in[3];     // [N, 512] int32
    float*       out    = (float*)d_out;
    const int    N      = in_sizes[2];             // 1024 tokens
    const int    nocc   = N * NLOG;                // 525312

    // ws layout (u32/f32 elements)
    unsigned int* counts     = (unsigned int*)d_ws;
    unsigned int* cursor     = counts + VOCAB;
    unsigned int* sorted_v   = cursor + VOCAB;
    unsigned int* sorted_pay = sorted_v + nocc;
    float*        logits     = (float*)(sorted_pay + nocc);
    float*        loss       = logits + nocc;
    const size_t  need_bytes = (size_t)(2 * VOCAB + 3 * nocc + N) * 4;

    if (ws_size < need_bytes) {
        // fallback: direct gather path (R1)
        float* ws = (float*)d_ws;
        nce_token_kernel<<<N, 512, 0, stream>>>(h, W, target, noise, ws);
        reduce_mean_kernel<<<1, 256, 0, stream>>>(ws, out, N);
        return;
    }

    zero_kernel<<<(VOCAB + 255) / 256, 256, 0, stream>>>(counts, VOCAB);
    hist_kernel<<<512, 256, 0, stream>>>(target, noise, counts, N);
    scan_kernel<<<1, 1024, 0, stream>>>(counts, cursor);
    scatter_kernel<<<512, 256, 0, stream>>>(target, noise, cursor,
                                            sorted_v, sorted_pay, N);
    const int nwaves  = (nocc + 63) / 64;
    const int gblocks = (nwaves + (GTPB / 64) - 1) / (GTPB / 64);
    gather_dot_kernel<<<gblocks, GTPB, 0, stream>>>(h, W, sorted_v, sorted_pay,
                                                    logits, nocc);
    softmax_loss_kernel<<<N, 256, 0, stream>>>(logits, loss);
    reduce_mean_kernel<<<1, 256, 0, stream>>>(loss, out, N);
}